// Round 8
// baseline (391.097 us; speedup 1.0000x reference)
//
#include <hip/hip_runtime.h>
#include <hip/hip_bf16.h>
#include <cstdint>

#define E_N   512
#define C_N   64
#define HW_N  784
#define CHW_N 50176     // C_N * HW_N
#define CHW4  12544
#define NC    256

typedef __attribute__((ext_vector_type(8))) short bf16x8;
typedef __attribute__((ext_vector_type(4))) float f32x4;
typedef __attribute__((ext_vector_type(8))) unsigned short us8;

// exact RNE f32 -> bf16 (no NaN inputs here)
__device__ __forceinline__ unsigned short bf16_rne(float f, float& hif) {
    unsigned int u = __float_as_uint(f);
    unsigned int r = u + 0x7FFFu + ((u >> 16) & 1u);
    unsigned short h = (unsigned short)(r >> 16);
    hif = __uint_as_float((unsigned int)h << 16);
    return h;
}

// ---------------- kernel 1: CSR adjacency + inv_count + W split (bf16 hi/lo) --
__global__ void prep_k(const int* __restrict__ ec, const float* __restrict__ W,
                       int* __restrict__ adj_start, int* __restrict__ adj_edge,
                       float* __restrict__ inv_count,
                       unsigned short* __restrict__ Whi, unsigned short* __restrict__ Wlo)
{
    __shared__ int cnt[NC];
    __shared__ int st[NC + 1];
    int tid = threadIdx.x;
    if (tid < NC) cnt[tid] = 0;
    __syncthreads();
    for (int e = tid; e < E_N; e += 256) {
        atomicAdd(&cnt[ec[2 * e] & (NC - 1)], 1);
        atomicAdd(&cnt[ec[2 * e + 1] & (NC - 1)], 1);
    }
    __syncthreads();
    if (tid == 0) {
        int s = 0;
        for (int c = 0; c < NC; ++c) { st[c] = s; s += cnt[c]; }
        st[NC] = s;
    }
    __syncthreads();
    if (tid < NC) {
        adj_start[tid] = st[tid];
        inv_count[tid] = 1.0f / (float)((cnt[tid] > 1) ? cnt[tid] : 1);
        cnt[tid] = st[tid];
    }
    if (tid == 0) adj_start[NC] = st[NC];
    __syncthreads();
    for (int e = tid; e < E_N; e += 256) {
        adj_edge[atomicAdd(&cnt[ec[2 * e] & (NC - 1)], 1)] = e;
        adj_edge[atomicAdd(&cnt[ec[2 * e + 1] & (NC - 1)], 1)] = e;
    }
    // split first 192 cols of W_agg (row-major [o][256]) into bf16 hi/lo [o][192]
    for (int i = tid; i < 64 * 192; i += 256) {
        int o = i / 192, k = i - o * 192;
        float w = W[o * 256 + k];
        float hif;
        unsigned short hi = bf16_rne(w, hif);
        float d;
        unsigned short lo = bf16_rne(w - hif, d);
        Whi[i] = hi;
        Wlo[i] = lo;
    }
}

// ---------------- kernel 2: global max over edges, partial (8 chunks), f4 ----
__global__ void gmax_part_k(const float* __restrict__ x, float* __restrict__ part)
{
    int p4 = blockIdx.x * 256 + threadIdx.x;
    const float4* p = reinterpret_cast<const float4*>(x) + (size_t)(blockIdx.y * 64) * CHW4 + p4;
    float4 m = make_float4(-INFINITY, -INFINITY, -INFINITY, -INFINITY);
    #pragma unroll 4
    for (int i = 0; i < 64; ++i) {
        float4 v = p[(size_t)i * CHW4];
        m.x = fmaxf(m.x, v.x); m.y = fmaxf(m.y, v.y);
        m.z = fmaxf(m.z, v.z); m.w = fmaxf(m.w, v.w);
    }
    reinterpret_cast<float4*>(part)[blockIdx.y * CHW4 + p4] = m;
}

// ---------------- kernel 3: reduce the 8 partials (f4) -----------------------
__global__ void gmax_reduce_k(const float* __restrict__ part, float* __restrict__ gmax)
{
    int p4 = blockIdx.x * 256 + threadIdx.x;
    const float4* p = reinterpret_cast<const float4*>(part);
    float4 m = p[p4];
    #pragma unroll
    for (int i = 1; i < 8; ++i) {
        float4 v = p[i * CHW4 + p4];
        m.x = fmaxf(m.x, v.x); m.y = fmaxf(m.y, v.y);
        m.z = fmaxf(m.z, v.z); m.w = fmaxf(m.w, v.w);
    }
    reinterpret_cast<float4*>(gmax)[p4] = m;
}

// ---------------- kernel 4: G4[o,hw] = sum_c W4[o,c]*gmax[c,hw] (fp32) ------
__global__ void g4_k(const float* __restrict__ W, const float* __restrict__ gmax,
                     float* __restrict__ g4)
{
    int j4 = blockIdx.x * 256 + threadIdx.x;
    int o  = (j4 * 4) / HW_N;
    int hw = j4 * 4 - o * HW_N;
    float4 acc = make_float4(0.f, 0.f, 0.f, 0.f);
    #pragma unroll 8
    for (int c = 0; c < 64; ++c) {
        float w = W[o * 256 + 192 + c];
        float4 g = *reinterpret_cast<const float4*>(gmax + c * HW_N + hw);
        acc.x += w * g.x; acc.y += w * g.y; acc.z += w * g.z; acc.w += w * g.w;
    }
    *reinterpret_cast<float4*>(g4 + (size_t)j4 * 4) = acc;
}

// ---------------- kernel 5: corner features (segment mean, fp32) -------------
__global__ void cf_k(const float* __restrict__ x, const int* __restrict__ adj_start,
                     const int* __restrict__ adj_edge, const float* __restrict__ inv_count,
                     float* __restrict__ cf)
{
    int c  = blockIdx.y;
    int p4 = blockIdx.x * 256 + threadIdx.x;
    float4 acc = make_float4(0.f, 0.f, 0.f, 0.f);
    int s0 = adj_start[c], s1 = adj_start[c + 1];
    for (int i = s0; i < s1; ++i) {
        int e = adj_edge[i];
        float4 v = *reinterpret_cast<const float4*>(x + (size_t)e * CHW_N + (size_t)p4 * 4);
        acc.x += v.x; acc.y += v.y; acc.z += v.z; acc.w += v.w;
    }
    float ic = inv_count[c];
    acc.x *= ic; acc.y *= ic; acc.z *= ic; acc.w *= ic;
    *reinterpret_cast<float4*>(cf + (size_t)c * CHW_N + (size_t)p4 * 4) = acc;
}

// ---------------- kernel 6: fused MFMA matmul (split-bf16) + G4 + relu -------
// out[o, j] = relu( sum_{k<192} W[o][k] * B[k][j] + G4[o, hw(j)] )
// B rows: 0..63 = x[e(j)], 64..127 = cf[c0], 128..191 = cf[c1]
// Split fp32 = hi + lo (bf16); product via 3 MFMAs: Wh*Bh + Wh*Bl + Wl*Bh.
// Block: 256 thr (4 waves), output o64 x j128; wave w owns j32 slice (2 j-tiles).
__global__ __launch_bounds__(256) void fused_mfma_k(
    const float* __restrict__ x, const float* __restrict__ cf,
    const unsigned short* __restrict__ Whi, const unsigned short* __restrict__ Wlo,
    const float* __restrict__ g4, const int* __restrict__ ec,
    float* __restrict__ out)
{
    // rows padded to 40 ushort (80 B): keeps every row 16B-aligned for b128,
    // 80B stride -> ~2-way bank aliasing (free per m136)
    __shared__ unsigned short Ah[64][40], Al[64][40];
    __shared__ unsigned short Bh[128][40], Bl[128][40];
    __shared__ const float* sb[3][8];
    __shared__ int eArr[8], hwArr[8];

    int tid = threadIdx.x;
    int jbase = blockIdx.x * 128;

    if (tid < 8) {
        int j16 = jbase + tid * 16;      // 784 % 16 == 0: each 16-col group is one edge
        int e   = j16 / HW_N;
        int hw0 = j16 - e * HW_N;
        eArr[tid]  = e;
        hwArr[tid] = hw0;
        int c0 = ec[2 * e]     & (NC - 1);
        int c1 = ec[2 * e + 1] & (NC - 1);
        sb[0][tid] = x  + (size_t)e  * CHW_N + hw0;
        sb[1][tid] = cf + (size_t)c0 * CHW_N + hw0;
        sb[2][tid] = cf + (size_t)c1 * CHW_N + hw0;
    }
    __syncthreads();

    int lane  = tid & 63;
    int wv    = tid >> 6;
    int row16 = lane & 15;
    int kq    = (lane >> 4) << 3;     // k-offset within frag: 0,8,16,24

    f32x4 acc[4][2];
    #pragma unroll
    for (int a = 0; a < 4; ++a)
        #pragma unroll
        for (int b = 0; b < 2; ++b) acc[a][b] = (f32x4){0.f, 0.f, 0.f, 0.f};

    int ao  = tid >> 2;               // A-staging: row o (0..63)
    int akq = (tid & 3) << 3;         // k-chunk 0,8,16,24

    for (int s = 0; s < 6; ++s) {
        int seg   = s >> 1;           // 0:x 1:cf[c0] 2:cf[c1]
        int krel0 = (s & 1) << 5;     // row offset within the 64-row segment
        int k0    = s << 5;           // global k offset (into Whi/Wlo)

        // ---- stage A (W hi/lo), 64x32 bf16 each, b128 copies ----
        *reinterpret_cast<us8*>(&Ah[ao][akq]) =
            *reinterpret_cast<const us8*>(Whi + ao * 192 + k0 + akq);
        *reinterpret_cast<us8*>(&Al[ao][akq]) =
            *reinterpret_cast<const us8*>(Wlo + ao * 192 + k0 + akq);

        // ---- stage B: load f32 [k][j], split, TRANSPOSE to [j][k] bf16 ----
        #pragma unroll
        for (int it = 0; it < 4; ++it) {
            int idx = it * 256 + tid;         // 0..1023
            int kl  = idx >> 5;               // 0..31
            int j4  = idx & 31;               // j = j4*4
            const float* src = sb[seg][j4 >> 2] + (krel0 + kl) * HW_N + (j4 & 3) * 4;
            float4 v = *reinterpret_cast<const float4*>(src);
            int jrow = j4 << 2;
            float fv[4] = {v.x, v.y, v.z, v.w};
            #pragma unroll
            for (int m = 0; m < 4; ++m) {
                float hif;
                unsigned short hi = bf16_rne(fv[m], hif);
                float d;
                unsigned short lo = bf16_rne(fv[m] - hif, d);
                Bh[jrow + m][kl] = hi;
                Bl[jrow + m][kl] = lo;
            }
        }
        __syncthreads();

        // ---- frags ----
        bf16x8 ah[4], al[4], bh[2], bl[2];
        #pragma unroll
        for (int ot = 0; ot < 4; ++ot) {
            ah[ot] = *reinterpret_cast<const bf16x8*>(&Ah[ot * 16 + row16][kq]);
            al[ot] = *reinterpret_cast<const bf16x8*>(&Al[ot * 16 + row16][kq]);
        }
        #pragma unroll
        for (int jt = 0; jt < 2; ++jt) {
            bh[jt] = *reinterpret_cast<const bf16x8*>(&Bh[wv * 32 + jt * 16 + row16][kq]);
            bl[jt] = *reinterpret_cast<const bf16x8*>(&Bl[wv * 32 + jt * 16 + row16][kq]);
        }

        // ---- 24 MFMAs: 4 o-tiles x 2 j-tiles x 3 splits ----
        #pragma unroll
        for (int ot = 0; ot < 4; ++ot)
            #pragma unroll
            for (int jt = 0; jt < 2; ++jt) {
                acc[ot][jt] = __builtin_amdgcn_mfma_f32_16x16x32_bf16(ah[ot], bh[jt], acc[ot][jt], 0, 0, 0);
                acc[ot][jt] = __builtin_amdgcn_mfma_f32_16x16x32_bf16(ah[ot], bl[jt], acc[ot][jt], 0, 0, 0);
                acc[ot][jt] = __builtin_amdgcn_mfma_f32_16x16x32_bf16(al[ot], bh[jt], acc[ot][jt], 0, 0, 0);
            }
        __syncthreads();
    }

    // ---- epilogue: + G4, relu, store (D: col=lane&15, row=(lane>>4)*4+reg) --
    int orb = (lane >> 4) << 2;
    #pragma unroll
    for (int ot = 0; ot < 4; ++ot)
        #pragma unroll
        for (int jt = 0; jt < 2; ++jt) {
            int g  = wv * 2 + jt;
            int e  = eArr[g];
            int hw = hwArr[g] + row16;
            #pragma unroll
            for (int r = 0; r < 4; ++r) {
                int o = ot * 16 + orb + r;
                float v = acc[ot][jt][r] + g4[o * HW_N + hw];
                out[(size_t)e * CHW_N + o * HW_N + hw] = fmaxf(v, 0.f);
            }
        }
}

// ---------------- launch ----------------
extern "C" void kernel_launch(void* const* d_in, const int* in_sizes, int n_in,
                              void* d_out, int out_size, void* d_ws, size_t ws_size,
                              hipStream_t stream)
{
    const float* x  = (const float*)d_in[0];
    const float* W  = (const float*)d_in[1];
    const int*   ec = (const int*)d_in[3];    // edge_corner (E,2) int32
    float* out      = (float*)d_out;

    // workspace layout (floats)
    float* ws_f      = (float*)d_ws;
    float* cf        = ws_f;                        // 12,845,056
    float* part      = cf + (size_t)NC * CHW_N;     // 401,408
    float* gmax      = part + 8 * CHW_N;            // 50,176
    float* g4        = gmax + CHW_N;                // 50,176
    unsigned short* Whi = (unsigned short*)(g4 + CHW_N);  // 12,288 us
    unsigned short* Wlo = Whi + 12288;                    // 12,288 us
    int*   adj_start = (int*)(Wlo + 12288);         // 257 (pad 272)
    int*   adj_edge  = adj_start + 272;             // 1024
    float* inv_count = (float*)(adj_edge + 1024);   // 256

    prep_k<<<1, 256, 0, stream>>>(ec, W, adj_start, adj_edge, inv_count, Whi, Wlo);
    gmax_part_k<<<dim3(49, 8), 256, 0, stream>>>(x, part);
    gmax_reduce_k<<<49, 256, 0, stream>>>(part, gmax);
    g4_k<<<49, 256, 0, stream>>>(W, gmax, g4);
    cf_k<<<dim3(49, NC), 256, 0, stream>>>(x, adj_start, adj_edge, inv_count, cf);
    fused_mfma_k<<<3136, 256, 0, stream>>>(x, cf, Whi, Wlo, g4, ec, out);
}

// Round 9
// 303.181 us; speedup vs baseline: 1.2900x; 1.2900x over previous
//
#include <hip/hip_runtime.h>
#include <hip/hip_bf16.h>
#include <cstdint>

#define E_N   512
#define C_N   64
#define HW_N  784
#define CHW_N 50176     // C_N * HW_N
#define CHW4  12544
#define NC    256

typedef __attribute__((ext_vector_type(8))) short bf16x8;
typedef __attribute__((ext_vector_type(4))) float f32x4;
typedef __attribute__((ext_vector_type(8))) unsigned short us8;

// exact RNE f32 -> bf16 (no NaN inputs here)
__device__ __forceinline__ unsigned short bf16_rne(float f, float& hif) {
    unsigned int u = __float_as_uint(f);
    unsigned int r = u + 0x7FFFu + ((u >> 16) & 1u);
    unsigned short h = (unsigned short)(r >> 16);
    hif = __uint_as_float((unsigned int)h << 16);
    return h;
}

// 8 f32 -> bf16x8 hi + bf16x8 lo, all in registers (RNE via v_cvt_pk_bf16_f32)
__device__ __forceinline__ void cvt8(const float* f, bf16x8& hi, bf16x8& lo) {
    unsigned int hw_[4], lw_[4];
    #pragma unroll
    for (int p = 0; p < 4; ++p) {
        float a = f[2 * p], b = f[2 * p + 1];
        unsigned int hp;
        asm("v_cvt_pk_bf16_f32 %0, %1, %2" : "=v"(hp) : "v"(a), "v"(b));
        float ha = __uint_as_float(hp << 16);
        float hb = __uint_as_float(hp & 0xFFFF0000u);
        float la = a - ha, lb = b - hb;
        unsigned int lp;
        asm("v_cvt_pk_bf16_f32 %0, %1, %2" : "=v"(lp) : "v"(la), "v"(lb));
        hw_[p] = hp; lw_[p] = lp;
    }
    union { unsigned int u[4]; bf16x8 v; } cu, cl;
    #pragma unroll
    for (int p = 0; p < 4; ++p) { cu.u[p] = hw_[p]; cl.u[p] = lw_[p]; }
    hi = cu.v; lo = cl.v;
}

// ---------------- kernel 1: CSR adjacency + inv_count + W split (bf16 hi/lo) --
__global__ void prep_k(const int* __restrict__ ec, const float* __restrict__ W,
                       int* __restrict__ adj_start, int* __restrict__ adj_edge,
                       float* __restrict__ inv_count,
                       unsigned short* __restrict__ Whi, unsigned short* __restrict__ Wlo)
{
    __shared__ int cnt[NC];
    __shared__ int st[NC + 1];
    int tid = threadIdx.x;
    if (tid < NC) cnt[tid] = 0;
    __syncthreads();
    for (int e = tid; e < E_N; e += 256) {
        atomicAdd(&cnt[ec[2 * e] & (NC - 1)], 1);
        atomicAdd(&cnt[ec[2 * e + 1] & (NC - 1)], 1);
    }
    __syncthreads();
    if (tid == 0) {
        int s = 0;
        for (int c = 0; c < NC; ++c) { st[c] = s; s += cnt[c]; }
        st[NC] = s;
    }
    __syncthreads();
    if (tid < NC) {
        adj_start[tid] = st[tid];
        inv_count[tid] = 1.0f / (float)((cnt[tid] > 1) ? cnt[tid] : 1);
        cnt[tid] = st[tid];
    }
    if (tid == 0) adj_start[NC] = st[NC];
    __syncthreads();
    for (int e = tid; e < E_N; e += 256) {
        adj_edge[atomicAdd(&cnt[ec[2 * e] & (NC - 1)], 1)] = e;
        adj_edge[atomicAdd(&cnt[ec[2 * e + 1] & (NC - 1)], 1)] = e;
    }
    // split first 192 cols of W_agg (row-major [o][256]) into bf16 hi/lo [o][192]
    for (int i = tid; i < 64 * 192; i += 256) {
        int o = i / 192, k = i - o * 192;
        float w = W[o * 256 + k];
        float hif;
        unsigned short hi = bf16_rne(w, hif);
        float d;
        unsigned short lo = bf16_rne(w - hif, d);
        Whi[i] = hi;
        Wlo[i] = lo;
    }
}

// ---------------- kernel 2: global max over edges, partial (8 chunks), f4 ----
__global__ void gmax_part_k(const float* __restrict__ x, float* __restrict__ part)
{
    int p4 = blockIdx.x * 256 + threadIdx.x;
    const float4* p = reinterpret_cast<const float4*>(x) + (size_t)(blockIdx.y * 64) * CHW4 + p4;
    float4 m = make_float4(-INFINITY, -INFINITY, -INFINITY, -INFINITY);
    #pragma unroll 4
    for (int i = 0; i < 64; ++i) {
        float4 v = p[(size_t)i * CHW4];
        m.x = fmaxf(m.x, v.x); m.y = fmaxf(m.y, v.y);
        m.z = fmaxf(m.z, v.z); m.w = fmaxf(m.w, v.w);
    }
    reinterpret_cast<float4*>(part)[blockIdx.y * CHW4 + p4] = m;
}

// ---------------- kernel 3: reduce the 8 partials (f4) -----------------------
__global__ void gmax_reduce_k(const float* __restrict__ part, float* __restrict__ gmax)
{
    int p4 = blockIdx.x * 256 + threadIdx.x;
    const float4* p = reinterpret_cast<const float4*>(part);
    float4 m = p[p4];
    #pragma unroll
    for (int i = 1; i < 8; ++i) {
        float4 v = p[i * CHW4 + p4];
        m.x = fmaxf(m.x, v.x); m.y = fmaxf(m.y, v.y);
        m.z = fmaxf(m.z, v.z); m.w = fmaxf(m.w, v.w);
    }
    reinterpret_cast<float4*>(gmax)[p4] = m;
}

// ---------------- kernel 4: G4[o,hw] = sum_c W4[o,c]*gmax[c,hw] (fp32) ------
__global__ void g4_k(const float* __restrict__ W, const float* __restrict__ gmax,
                     float* __restrict__ g4)
{
    int j4 = blockIdx.x * 256 + threadIdx.x;
    int o  = (j4 * 4) / HW_N;
    int hw = j4 * 4 - o * HW_N;
    float4 acc = make_float4(0.f, 0.f, 0.f, 0.f);
    #pragma unroll 8
    for (int c = 0; c < 64; ++c) {
        float w = W[o * 256 + 192 + c];
        float4 g = *reinterpret_cast<const float4*>(gmax + c * HW_N + hw);
        acc.x += w * g.x; acc.y += w * g.y; acc.z += w * g.z; acc.w += w * g.w;
    }
    *reinterpret_cast<float4*>(g4 + (size_t)j4 * 4) = acc;
}

// ---------------- kernel 5: corner features (segment mean, fp32) -------------
__global__ void cf_k(const float* __restrict__ x, const int* __restrict__ adj_start,
                     const int* __restrict__ adj_edge, const float* __restrict__ inv_count,
                     float* __restrict__ cf)
{
    int c  = blockIdx.y;
    int p4 = blockIdx.x * 256 + threadIdx.x;
    float4 acc = make_float4(0.f, 0.f, 0.f, 0.f);
    int s0 = adj_start[c], s1 = adj_start[c + 1];
    for (int i = s0; i < s1; ++i) {
        int e = adj_edge[i];
        float4 v = *reinterpret_cast<const float4*>(x + (size_t)e * CHW_N + (size_t)p4 * 4);
        acc.x += v.x; acc.y += v.y; acc.z += v.z; acc.w += v.w;
    }
    float ic = inv_count[c];
    acc.x *= ic; acc.y *= ic; acc.z *= ic; acc.w *= ic;
    *reinterpret_cast<float4*>(cf + (size_t)c * CHW_N + (size_t)p4 * 4) = acc;
}

// ---------------- kernel 6: fused MFMA matmul (split-bf16) + G4 + relu -------
// out[o, j] = relu( sum_{k<192} W[o][k] * B[k][j] + G4[o, hw(j)] )
// B rows: 0..63 = x[e(j)], 64..127 = cf[c0], 128..191 = cf[c1]
// R8 post-mortem: LDS B-transpose was a 16-way write conflict (73% of cycles).
// Now: B fragments load k-strided f32 DIRECTLY global->reg (quarter-wave = 16
// consecutive j = 64B coalesced), convert in reg via v_cvt_pk_bf16_f32.
// A (W hi/lo) staged to LDS once ([64][200] rows: bank quad (r+q)%8 -> 2-way,
// free). Zero barriers in the k-loop.
__global__ __launch_bounds__(256) void fused_mfma_k(
    const float* __restrict__ x, const float* __restrict__ cf,
    const unsigned short* __restrict__ Whi, const unsigned short* __restrict__ Wlo,
    const float* __restrict__ g4, const int* __restrict__ ec,
    float* __restrict__ out)
{
    __shared__ unsigned short Ah[64][200], Al[64][200];
    __shared__ const float* sb[3][8];
    __shared__ int eArr[8], hwArr[8];

    int tid = threadIdx.x;
    int jbase = blockIdx.x * 128;

    if (tid < 8) {
        int j16 = jbase + tid * 16;      // 784 % 16 == 0: each 16-col group is one edge
        int e   = j16 / HW_N;
        int hw0 = j16 - e * HW_N;
        eArr[tid]  = e;
        hwArr[tid] = hw0;
        int c0 = ec[2 * e]     & (NC - 1);
        int c1 = ec[2 * e + 1] & (NC - 1);
        sb[0][tid] = x  + (size_t)e  * CHW_N + hw0;
        sb[1][tid] = cf + (size_t)c0 * CHW_N + hw0;
        sb[2][tid] = cf + (size_t)c1 * CHW_N + hw0;
    }

    // ---- stage ALL of W hi/lo (64 x 192) once ----
    #pragma unroll
    for (int i = 0; i < 6; ++i) {
        int chunk = tid + i * 256;           // 0..1535
        int row = chunk / 24, c8 = chunk % 24;
        *reinterpret_cast<us8*>(&Ah[row][c8 * 8]) =
            *reinterpret_cast<const us8*>(Whi + row * 192 + c8 * 8);
        *reinterpret_cast<us8*>(&Al[row][c8 * 8]) =
            *reinterpret_cast<const us8*>(Wlo + row * 192 + c8 * 8);
    }
    __syncthreads();

    int lane = tid & 63;
    int wv   = tid >> 6;
    int r16  = lane & 15;        // j within jt-tile / o-row within o-tile
    int q    = lane >> 4;        // k-octet: kq = q*8

    f32x4 acc[4][2];
    #pragma unroll
    for (int a = 0; a < 4; ++a)
        #pragma unroll
        for (int b = 0; b < 2; ++b) acc[a][b] = (f32x4){0.f, 0.f, 0.f, 0.f};

    // per-lane global bases for B fragments: (j = r16 within group, k = q*8)
    const float* pB[3][2];
    #pragma unroll
    for (int seg = 0; seg < 3; ++seg)
        #pragma unroll
        for (int jt = 0; jt < 2; ++jt)
            pB[seg][jt] = sb[seg][wv * 2 + jt] + q * 8 * HW_N + r16;

    #pragma unroll
    for (int s = 0; s < 6; ++s) {
        const int seg = s >> 1;            // 0:x 1:cf[c0] 2:cf[c1]
        const int kr0 = (s & 1) * 32;      // k-row offset within segment
        const int k0  = s * 32;            // k offset into Ah/Al

        // ---- B: 8 k-strided f32 per jt, straight to registers ----
        float f0[8], f1[8];
        #pragma unroll
        for (int i = 0; i < 8; ++i) f0[i] = pB[seg][0][(kr0 + i) * HW_N];
        #pragma unroll
        for (int i = 0; i < 8; ++i) f1[i] = pB[seg][1][(kr0 + i) * HW_N];

        // ---- A frags from LDS ----
        bf16x8 ah[4], al[4];
        #pragma unroll
        for (int ot = 0; ot < 4; ++ot) {
            ah[ot] = *reinterpret_cast<const bf16x8*>(&Ah[ot * 16 + r16][k0 + q * 8]);
            al[ot] = *reinterpret_cast<const bf16x8*>(&Al[ot * 16 + r16][k0 + q * 8]);
        }

        // ---- convert B in registers ----
        bf16x8 bh[2], bl[2];
        cvt8(f0, bh[0], bl[0]);
        cvt8(f1, bh[1], bl[1]);

        // ---- 24 MFMAs: 4 o-tiles x 2 j-tiles x 3 splits ----
        #pragma unroll
        for (int ot = 0; ot < 4; ++ot)
            #pragma unroll
            for (int jt = 0; jt < 2; ++jt) {
                acc[ot][jt] = __builtin_amdgcn_mfma_f32_16x16x32_bf16(ah[ot], bh[jt], acc[ot][jt], 0, 0, 0);
                acc[ot][jt] = __builtin_amdgcn_mfma_f32_16x16x32_bf16(ah[ot], bl[jt], acc[ot][jt], 0, 0, 0);
                acc[ot][jt] = __builtin_amdgcn_mfma_f32_16x16x32_bf16(al[ot], bh[jt], acc[ot][jt], 0, 0, 0);
            }
    }

    // ---- epilogue: + G4, relu, store (D: col=lane&15, row=(lane>>4)*4+reg) --
    int orb = q << 2;
    #pragma unroll
    for (int ot = 0; ot < 4; ++ot)
        #pragma unroll
        for (int jt = 0; jt < 2; ++jt) {
            int g  = wv * 2 + jt;
            int e  = eArr[g];
            int hw = hwArr[g] + r16;
            #pragma unroll
            for (int r = 0; r < 4; ++r) {
                int o = ot * 16 + orb + r;
                float v = acc[ot][jt][r] + g4[o * HW_N + hw];
                out[(size_t)e * CHW_N + o * HW_N + hw] = fmaxf(v, 0.f);
            }
        }
}

// ---------------- launch ----------------
extern "C" void kernel_launch(void* const* d_in, const int* in_sizes, int n_in,
                              void* d_out, int out_size, void* d_ws, size_t ws_size,
                              hipStream_t stream)
{
    const float* x  = (const float*)d_in[0];
    const float* W  = (const float*)d_in[1];
    const int*   ec = (const int*)d_in[3];    // edge_corner (E,2) int32
    float* out      = (float*)d_out;

    // workspace layout (floats)
    float* ws_f      = (float*)d_ws;
    float* cf        = ws_f;                        // 12,845,056
    float* part      = cf + (size_t)NC * CHW_N;     // 401,408
    float* gmax      = part + 8 * CHW_N;            // 50,176
    float* g4        = gmax + CHW_N;                // 50,176
    unsigned short* Whi = (unsigned short*)(g4 + CHW_N);  // 12,288 us
    unsigned short* Wlo = Whi + 12288;                    // 12,288 us
    int*   adj_start = (int*)(Wlo + 12288);         // 257 (pad 272)
    int*   adj_edge  = adj_start + 272;             // 1024
    float* inv_count = (float*)(adj_edge + 1024);   // 256

    prep_k<<<1, 256, 0, stream>>>(ec, W, adj_start, adj_edge, inv_count, Whi, Wlo);
    gmax_part_k<<<dim3(49, 8), 256, 0, stream>>>(x, part);
    gmax_reduce_k<<<49, 256, 0, stream>>>(part, gmax);
    g4_k<<<49, 256, 0, stream>>>(W, gmax, g4);
    cf_k<<<dim3(49, NC), 256, 0, stream>>>(x, adj_start, adj_edge, inv_count, cf);
    fused_mfma_k<<<3136, 256, 0, stream>>>(x, cf, Whi, Wlo, g4, ec, out);
}